// Round 7
// baseline (88.459 us; speedup 1.0000x reference)
//
#include <hip/hip_runtime.h>

// YOLO layer: input [B=16, A*C=255, G=76, G=76] f32, anchors [3,2] f32.
// Output [B, A*G*G=17328, C=85] f32.
//   c=0: (sigmoid+gx)*8, c=1: (sigmoid+gy)*8, c=2: exp*aw, c=3: exp*ah,
//   c>=4: sigmoid   (anchor/stride scaling folded: (e^w * aw/8)*8 == e^w*aw)
//
// R3 structure (best 37.2us: persistent grid-stride + register prefetch +
// __syncthreads).
//   R4 lesson: lgkmcnt-only barriers REGRESSED (outstanding stores serialize
//     in the vmcnt FIFO + L2 write pressure) -- keep __syncthreads.
//   R5 lesson: nontemporal stores REGRESSED 2x on gfx950 (write-through /
//     sub-line HBM writes: WRITE 92->226MB, FETCH 58->122MB) -- plain stores.
// NEW: native transcendentals. sigmoid = v_exp_f32 + v_add + v_rcp_f32
// (no libm range checks, no Newton iteration). absmax threshold 496 >> 2ulp.

#define GDIM 76
#define GG 5776            // 76*76 (divisible by 4)
#define NA 3
#define NCH 85
#define TILE 64            // spatial positions per block-tile
#define THREADS 256        // 4 waves
#define LOAD_UNITS (NCH * (TILE / 4))  // 1360 float4 units per tile
#define LITERS 6                       // ceil(1360/256)
#define TPB 91                         // tiles per (b,a): ceil(5776/64)
#define NT (TPB * NA * 16)             // 4368 total tiles
#define GRID 1792                      // 7 blocks/CU * 256 CUs (LDS cap)

typedef float f32x4 __attribute__((ext_vector_type(4)));

__device__ __forceinline__ float fast_sigmoid(float x) {
    // 1/(1+exp(-x)): v_exp_f32 (via __expf) + v_rcp_f32 (no NR refinement)
    return __builtin_amdgcn_rcpf(1.0f + __expf(-x));
}

__global__ __launch_bounds__(THREADS) void yolo_kernel(
    const float* __restrict__ in, const float* __restrict__ anchors,
    float* __restrict__ out)
{
    __shared__ float lds[TILE * NCH];   // 21760 B -> 7 blocks/CU

    const int t = threadIdx.x;

    const float aw0 = anchors[0], ah0 = anchors[1];
    const float aw1 = anchors[2], ah1 = anchors[3];
    const float aw2 = anchors[4], ah2 = anchors[5];

    f32x4 v[LITERS];

    auto load_tile = [&](int g) {
        int ba   = g / TPB;
        int tile = g - ba * TPB;
        int s0   = tile * TILE;
        const float* inb = in + (long)ba * (NCH * GG);
        #pragma unroll
        for (int i = 0; i < LITERS; ++i) {
            int idx = t + i * THREADS;
            int c   = idx >> 4;
            int q   = idx & 15;
            int pos = s0 + q * 4;
            if (idx < LOAD_UNITS && pos < GG)
                v[i] = *reinterpret_cast<const f32x4*>(&inb[(long)c * GG + pos]);
        }
    };

    auto transform_write = [&](int g) {
        int ba   = g / TPB;
        int tile = g - ba * TPB;
        int a    = ba % NA;
        int s0   = tile * TILE;
        float aw = (a == 0) ? aw0 : (a == 1) ? aw1 : aw2;
        float ah = (a == 0) ? ah0 : (a == 1) ? ah1 : ah2;
        #pragma unroll
        for (int i = 0; i < LITERS; ++i) {
            int idx = t + i * THREADS;
            int c   = idx >> 4;
            int q   = idx & 15;
            int pos = s0 + q * 4;
            if (idx < LOAD_UNITS && pos < GG) {
                float r[4] = {v[i].x, v[i].y, v[i].z, v[i].w};
                if (c == 0) {
                    #pragma unroll
                    for (int k = 0; k < 4; ++k) {
                        int p = pos + k;
                        float gx = (float)(p - (p / GDIM) * GDIM);
                        r[k] = (fast_sigmoid(r[k]) + gx) * 8.0f;
                    }
                } else if (c == 1) {
                    #pragma unroll
                    for (int k = 0; k < 4; ++k) {
                        int p = pos + k;
                        float gy = (float)(p / GDIM);
                        r[k] = (fast_sigmoid(r[k]) + gy) * 8.0f;
                    }
                } else if (c == 2) {
                    #pragma unroll
                    for (int k = 0; k < 4; ++k) r[k] = __expf(r[k]) * aw;
                } else if (c == 3) {
                    #pragma unroll
                    for (int k = 0; k < 4; ++k) r[k] = __expf(r[k]) * ah;
                } else {
                    #pragma unroll
                    for (int k = 0; k < 4; ++k) r[k] = fast_sigmoid(r[k]);
                }
                #pragma unroll
                for (int k = 0; k < 4; ++k)
                    lds[(q * 4 + k) * NCH + c] = r[k];
            }
        }
    };

    auto store_tile = [&](int g) {
        int ba    = g / TPB;
        int tile  = g - ba * TPB;
        int s0    = tile * TILE;
        int valid = (GG - s0 < TILE) ? (GG - s0) : TILE;  // 64 or 16
        int n4    = valid * NCH / 4;                       // 1360 or 340
        f32x4* __restrict__ outv =
            reinterpret_cast<f32x4*>(out + ((long)ba * GG + s0) * NCH);
        const f32x4* ldsv = reinterpret_cast<const f32x4*>(lds);
        #pragma unroll
        for (int i = 0; i < LITERS; ++i) {
            int f4 = t + i * THREADS;
            if (f4 < n4)
                outv[f4] = ldsv[f4];   // ds_read_b128 + global_store_dwordx4
        }
    };

    int g = blockIdx.x;
    load_tile(g);                       // prologue (every block has >=2 tiles)
    for (; g < NT; g += GRID) {
        transform_write(g);             // consumes v (vmcnt wait), fills LDS
        __syncthreads();
        int gn = g + GRID;
        if (gn < NT) load_tile(gn);     // issue next-tile loads
        store_tile(g);                  // LDS -> global
        __syncthreads();                // LDS drained before next overwrite
    }
}

extern "C" void kernel_launch(void* const* d_in, const int* in_sizes, int n_in,
                              void* d_out, int out_size, void* d_ws, size_t ws_size,
                              hipStream_t stream) {
    const float* pred    = (const float*)d_in[0];
    const float* anchors = (const float*)d_in[1];
    float* out           = (float*)d_out;

    yolo_kernel<<<dim3(GRID), dim3(THREADS), 0, stream>>>(pred, anchors, out);
}

// Round 8
// 35.908 us; speedup vs baseline: 2.4635x; 2.4635x over previous
//
#include <hip/hip_runtime.h>

// YOLO layer: input [B=16, A*C=255, G=76, G=76] f32, anchors [3,2] f32.
// Output [B, A*G*G=17328, C=85] f32.
//   c=0: (sigmoid+gx)*8, c=1: (sigmoid+gy)*8, c=2: exp*aw, c=3: exp*ah,
//   c>=4: sigmoid   (anchor/stride scaling folded: (e^w * aw/8)*8 == e^w*aw)
//
// EXACT R3 structure (best 37.2us: persistent grid-stride + register
// prefetch + __syncthreads + HIP float4 + per-tile anchor loads).
// R5/R6 (f32x4 ext_vector typedef + hoisted anchors) showed 356 MB HBM
// traffic vs R3's ~150 MB and 2.3x dur -- reverted wholesale. Only delta
// vs R3: native transcendentals (v_exp_f32 + v_rcp_f32), pure VALU.

#define GDIM 76
#define GG 5776            // 76*76 (divisible by 4)
#define NA 3
#define NCH 85
#define TILE 64            // spatial positions per block-tile
#define THREADS 256        // 4 waves
#define LOAD_UNITS (NCH * (TILE / 4))  // 1360 float4 units per tile
#define LITERS 6                       // ceil(1360/256)
#define TPB 91                         // tiles per (b,a): ceil(5776/64)
#define NT (TPB * NA * 16)             // 4368 total tiles
#define GRID 1792                      // 7 blocks/CU * 256 CUs (LDS cap)

__device__ __forceinline__ float fast_sigmoid(float x) {
    // 1/(1+exp(-x)): v_exp_f32 + v_add + v_rcp_f32 (no libm range checks,
    // no Newton refinement). ~2 ulp; absmax threshold is ~496.
    return __builtin_amdgcn_rcpf(1.0f + __expf(-x));
}

__global__ __launch_bounds__(THREADS) void yolo_kernel(
    const float* __restrict__ in, const float* __restrict__ anchors,
    float* __restrict__ out)
{
    __shared__ float lds[TILE * NCH];   // 21760 B -> 7 blocks/CU

    const int t = threadIdx.x;

    float4 v[LITERS];

    auto load_tile = [&](int g) {
        int ba   = g / TPB;
        int tile = g - ba * TPB;
        int s0   = tile * TILE;
        const float* inb = in + (long)ba * (NCH * GG);
        #pragma unroll
        for (int i = 0; i < LITERS; ++i) {
            int idx = t + i * THREADS;
            int c   = idx >> 4;
            int q   = idx & 15;
            int pos = s0 + q * 4;
            if (idx < LOAD_UNITS && pos < GG)
                v[i] = *reinterpret_cast<const float4*>(&inb[(long)c * GG + pos]);
        }
    };

    auto transform_write = [&](int g) {
        int ba   = g / TPB;
        int tile = g - ba * TPB;
        int a    = ba % NA;
        int s0   = tile * TILE;
        float aw = anchors[2 * a];
        float ah = anchors[2 * a + 1];
        #pragma unroll
        for (int i = 0; i < LITERS; ++i) {
            int idx = t + i * THREADS;
            int c   = idx >> 4;
            int q   = idx & 15;
            int pos = s0 + q * 4;
            if (idx < LOAD_UNITS && pos < GG) {
                float r[4] = {v[i].x, v[i].y, v[i].z, v[i].w};
                if (c == 0) {
                    #pragma unroll
                    for (int k = 0; k < 4; ++k) {
                        int p = pos + k;
                        float gx = (float)(p - (p / GDIM) * GDIM);
                        r[k] = (fast_sigmoid(r[k]) + gx) * 8.0f;
                    }
                } else if (c == 1) {
                    #pragma unroll
                    for (int k = 0; k < 4; ++k) {
                        int p = pos + k;
                        float gy = (float)(p / GDIM);
                        r[k] = (fast_sigmoid(r[k]) + gy) * 8.0f;
                    }
                } else if (c == 2) {
                    #pragma unroll
                    for (int k = 0; k < 4; ++k) r[k] = __expf(r[k]) * aw;
                } else if (c == 3) {
                    #pragma unroll
                    for (int k = 0; k < 4; ++k) r[k] = __expf(r[k]) * ah;
                } else {
                    #pragma unroll
                    for (int k = 0; k < 4; ++k) r[k] = fast_sigmoid(r[k]);
                }
                #pragma unroll
                for (int k = 0; k < 4; ++k)
                    lds[(q * 4 + k) * NCH + c] = r[k];
            }
        }
    };

    auto store_tile = [&](int g) {
        int ba    = g / TPB;
        int tile  = g - ba * TPB;
        int s0    = tile * TILE;
        int valid = (GG - s0 < TILE) ? (GG - s0) : TILE;  // 64 or 16
        int n4    = valid * NCH / 4;                       // 1360 or 340
        float4* __restrict__ outv =
            reinterpret_cast<float4*>(out + ((long)ba * GG + s0) * NCH);
        const float4* ldsv = reinterpret_cast<const float4*>(lds);
        #pragma unroll
        for (int i = 0; i < LITERS; ++i) {
            int f4 = t + i * THREADS;
            if (f4 < n4)
                outv[f4] = ldsv[f4];
        }
    };

    int g = blockIdx.x;
    load_tile(g);                       // prologue (every block has >=2 tiles)
    for (; g < NT; g += GRID) {
        transform_write(g);             // consumes v (vmcnt wait), fills LDS
        __syncthreads();
        int gn = g + GRID;
        if (gn < NT) load_tile(gn);     // issue next-tile loads: overlap stores
        store_tile(g);                  // LDS -> global
        __syncthreads();                // LDS drained before next overwrite
    }
}

extern "C" void kernel_launch(void* const* d_in, const int* in_sizes, int n_in,
                              void* d_out, int out_size, void* d_ws, size_t ws_size,
                              hipStream_t stream) {
    const float* pred    = (const float*)d_in[0];
    const float* anchors = (const float*)d_in[1];
    float* out           = (float*)d_out;

    yolo_kernel<<<dim3(GRID), dim3(THREADS), 0, stream>>>(pred, anchors, out);
}